// Round 6
// baseline (335.194 us; speedup 1.0000x reference)
//
#include <hip/hip_runtime.h>
#include <hip/hip_bf16.h>

#define N_NODES 65536
#define N_EDGES 524288

typedef __attribute__((ext_vector_type(8))) short bf16x8;
typedef __attribute__((ext_vector_type(4))) float f32x4;

__device__ __forceinline__ float bf2f(unsigned short u) {
    union { unsigned int i; float f; } v;
    v.i = ((unsigned int)u) << 16;
    return v.f;
}

// ---------------- init: deg=1 (self-loop), cnt=0 ------------------------------
__global__ void init_k(float* __restrict__ deg, int* __restrict__ cnt) {
    int i = blockIdx.x * 256 + threadIdx.x;
    deg[i] = 1.0f;
    cnt[i] = 0;
}
__global__ void deg_cnt_k(const int* __restrict__ dst, const float* __restrict__ w,
                          float* __restrict__ deg, int* __restrict__ cnt) {
    int e = blockIdx.x * 256 + threadIdx.x;
    int d = dst[e];
    atomicAdd(&deg[d], w[e]);
    atomicAdd(&cnt[d], 1);
}

// ------- scan: exclusive prefix sum + dinv = rsqrt(deg) + cursor copy ---------
__global__ __launch_bounds__(1024) void scan_k(const int* __restrict__ cnt,
                                               const float* __restrict__ deg,
                                               int* __restrict__ rp,
                                               int* __restrict__ cursor,
                                               float* __restrict__ dinv) {
    __shared__ int sums[1024];
    int t = threadIdx.x;
    int base = t * 64;
    int s = 0;
#pragma unroll
    for (int i = 0; i < 64; ++i) s += cnt[base + i];
    sums[t] = s;
    __syncthreads();
    for (int d = 1; d < 1024; d <<= 1) {
        int v = (t >= d) ? sums[t - d] : 0;
        __syncthreads();
        if (t >= d) sums[t] += v;
        __syncthreads();
    }
    int run = (t == 0) ? 0 : sums[t - 1];
#pragma unroll
    for (int i = 0; i < 64; ++i) {
        rp[base + i] = run;
        cursor[base + i] = run;
        dinv[base + i] = rsqrtf(deg[base + i]);
        run += cnt[base + i];
    }
    if (t == 1023) rp[65536] = run;
}

// ---------------- scatter edges into dst-sorted CSR order ---------------------
__global__ void scatter_k(const int* __restrict__ src, const int* __restrict__ dst,
                          const float* __restrict__ w, const float* __restrict__ dinv,
                          int* __restrict__ cursor, int* __restrict__ ssrc,
                          float* __restrict__ scoef) {
    int e = blockIdx.x * 256 + threadIdx.x;
    int s = src[e], d = dst[e];
    int pos = atomicAdd(&cursor[d], 1);
    ssrc[pos] = s;
    scoef[pos] = dinv[s] * w[e] * dinv[d];
}

// -------- merged weight/x prep: f2b(x) | f2b(wc1) | f2b(wc2) | wcomb ----------
// blocks [0,8192): x ; [8192,9216): wc1 ; [9216,9344): wc2 ; [9344,9600): wcomb
__global__ void prep_k(const float* __restrict__ x, __hip_bfloat16* __restrict__ xbf,
                       const float* __restrict__ wc1, __hip_bfloat16* __restrict__ wc1bf,
                       const float* __restrict__ wc2, __hip_bfloat16* __restrict__ wc2bf,
                       const float* __restrict__ w1, const float* __restrict__ wg,
                       __hip_bfloat16* __restrict__ WT) {
    int bid = blockIdx.x;
    if (bid < 9344) {
        const float* in;
        __hip_bfloat16* outp;
        int i;
        if (bid < 8192) { in = x; outp = xbf; i = bid * 1024 + threadIdx.x * 4; }
        else if (bid < 9216) { in = wc1; outp = wc1bf; i = (bid - 8192) * 1024 + threadIdx.x * 4; }
        else { in = wc2; outp = wc2bf; i = (bid - 9216) * 1024 + threadIdx.x * 4; }
        float4 v = *(const float4*)(in + i);
        alignas(8) __hip_bfloat16 tmp[4] = {__float2bfloat16(v.x), __float2bfloat16(v.y),
                                            __float2bfloat16(v.z), __float2bfloat16(v.w)};
        *(ushort4*)((unsigned short*)outp + i) = *(const ushort4*)tmp;
    } else {
        int t = (bid - 9344) * 256 + threadIdx.x;  // 512*128
        int f = t >> 7, c = t & 127;
        float s = 0.f;
#pragma unroll 8
        for (int m = 0; m < 128; ++m) s += w1[c * 128 + m] * wg[m * 512 + f];
        WT[t] = __float2bfloat16(s);  // WT[f*128 + c]
    }
}

// ---------------- gather SpMM on bf16 x: ybf[n] = bf16( P x )[n] ---------------
__global__ __launch_bounds__(256) void gather_k(const int* __restrict__ rp,
                                                const int* __restrict__ ssrc,
                                                const float* __restrict__ scoef,
                                                const unsigned short* __restrict__ xbf,
                                                const float* __restrict__ dinv,
                                                __hip_bfloat16* __restrict__ ybf) {
    int n = (blockIdx.x * 256 + threadIdx.x) >> 6;
    int lane = threadIdx.x & 63;
    int beg = rp[n], end = rp[n + 1];
    float di = dinv[n];
    float accx, accy;
    {
        unsigned int u = *(const unsigned int*)(xbf + (size_t)n * 128 + lane * 2);
        float c = di * di;
        accx = c * bf2f((unsigned short)(u & 0xffff));
        accy = c * bf2f((unsigned short)(u >> 16));
    }
    int s0 = 0;
    float c0 = 0.f;
    if (beg < end) { s0 = ssrc[beg]; c0 = scoef[beg]; }
    for (int i = beg; i < end; ++i) {
        int s1 = 0;
        float c1 = 0.f;
        if (i + 1 < end) { s1 = ssrc[i + 1]; c1 = scoef[i + 1]; }
        unsigned int u = *(const unsigned int*)(xbf + (size_t)s0 * 128 + lane * 2);
        accx += c0 * bf2f((unsigned short)(u & 0xffff));
        accy += c0 * bf2f((unsigned short)(u >> 16));
        s0 = s1;
        c0 = c1;
    }
    alignas(4) __hip_bfloat16 o[2] = {__float2bfloat16(accx), __float2bfloat16(accy)};
    *(unsigned int*)((unsigned short*)ybf + (size_t)n * 128 + lane * 2) =
        *(const unsigned int*)o;
}

// ---------------- async global -> LDS, 16B per lane ---------------------------
__device__ __forceinline__ void gll16(const void* g, void* l) {
    __builtin_amdgcn_global_load_lds(
        (const __attribute__((address_space(1))) void*)g,
        (__attribute__((address_space(3))) void*)l, 16, 0, 0);
}

// ---------------- bf16 MFMA GEMM, 2-phase double-buffered ---------------------
// C = act(A @ B^T + bias). A: MxK bf16 rm. B: NxK bf16 rm ((out,in) weights).
// ACT: 1 relu, 2 tanh.
// OUT_MODE: 1 bf16 rm, 2 bf16 rearrange-permute, 3 fused final dot -> atomicAdd
//           per-graph logits (Cout = float* logits, wlin used).
// SWIZ_NTX>0: 1D grid, XCD-chunked decode so the SWIZ_NTX column-blocks sharing
//             an A-panel run consecutively on ONE XCD (L2 A-reuse).
// 128x128 tile, BK=32, 4 waves (2x2), 4x4 16x16x32 frags; one barrier/K-step.
template <int ACT, int OUT_MODE, int SWIZ_NTX>
__global__ __launch_bounds__(256) void gemm_mfma_k(
    const __hip_bfloat16* __restrict__ A, const __hip_bfloat16* __restrict__ B,
    const float* __restrict__ bias, void* __restrict__ Cout,
    const float* __restrict__ wlin, int M, int N, int K) {
    __shared__ char lds[32768];  // 2 bufs x (A 8KB | B 8KB)

    const int tid = threadIdx.x;
    const int lane = tid & 63, wid = tid >> 6;
    int bx, by;
    if (SWIZ_NTX > 0) {
        int orig = blockIdx.x;
        int per = gridDim.x / (8 * SWIZ_NTX);  // y-tiles per XCD
        int xcd = orig & 7, k = orig >> 3;
        by = xcd * per + k / SWIZ_NTX;
        bx = k % SWIZ_NTX;
    } else {
        bx = blockIdx.x;
        by = blockIdx.y;
    }
    const int bm = by * 128, bn = bx * 128;
    const int wr = wid >> 1, wc = wid & 1;

    const int srow = wid * 16 + (lane >> 2);
    const int skcol = (lane & 3) * 8;
    const __hip_bfloat16* Abase = A + (size_t)(bm + srow) * K + skcol;
    const __hip_bfloat16* Bbase = B + (size_t)(bn + srow) * K + skcol;
    const int ldso = wid * 1024;

    f32x4 acc[4][4] = {};

    const int lrow = lane & 15;
    const int lkb = (lane >> 4) * 16;
    const int nk = K >> 5;

    auto stage = [&](int buf, int kt) {
        char* la = lds + buf * 16384;
        char* lb = la + 8192;
        gll16(Abase + kt * 32,                  la + ldso);
        gll16(Abase + kt * 32 + (size_t)64 * K, la + 4096 + ldso);
        gll16(Bbase + kt * 32,                  lb + ldso);
        gll16(Bbase + kt * 32 + (size_t)64 * K, lb + 4096 + ldso);
    };

    stage(0, 0);
    __syncthreads();  // drain vmcnt(0) + barrier: buf0 ready

    int cur = 0;
    for (int kt = 0; kt < nk; ++kt) {
        if (kt + 1 < nk) stage(cur ^ 1, kt + 1);  // prefetch hidden under compute
        const char* la = lds + cur * 16384;
        const char* lb = la + 8192;
        bf16x8 af[4], bfr[4];
#pragma unroll
        for (int i = 0; i < 4; ++i)
            af[i] = *(const bf16x8*)(la + (wr * 64 + i * 16 + lrow) * 64 + lkb);
#pragma unroll
        for (int j = 0; j < 4; ++j)
            bfr[j] = *(const bf16x8*)(lb + (wc * 64 + j * 16 + lrow) * 64 + lkb);
#pragma unroll
        for (int i = 0; i < 4; ++i)
#pragma unroll
            for (int j = 0; j < 4; ++j)
                acc[i][j] = __builtin_amdgcn_mfma_f32_16x16x32_bf16(
                    af[i], bfr[j], acc[i][j], 0, 0, 0);
        __syncthreads();  // drains prefetch vmcnt + syncs LDS reuse
        cur ^= 1;
    }

    // epilogue: C/D layout col=lane&15, row=(lane>>4)*4+reg
    const int crow0 = wr * 64 + (lane >> 4) * 4;
    const int ccol0 = wc * 64 + (lane & 15);
    if (OUT_MODE == 3) {
        float p0 = 0.f, p1 = 0.f;
#pragma unroll
        for (int i = 0; i < 4; ++i)
#pragma unroll
            for (int j = 0; j < 4; ++j) {
                int col = bn + ccol0 + j * 16;  // p index
                float bv = bias[col];
#pragma unroll
                for (int r = 0; r < 4; ++r) {
                    int rloc = crow0 + i * 16 + r;  // row within 128-block
                    float v = fmaxf(acc[i][j][r] + bv, 0.f);
                    float wl = wlin[col * 32 + (rloc & 31)];
                    if (i < 2) p0 += v * wl; else p1 += v * wl;
                }
            }
#pragma unroll
        for (int off = 32; off > 0; off >>= 1) {
            p0 += __shfl_down(p0, off, 64);
            p1 += __shfl_down(p1, off, 64);
        }
        if (lane == 0) {
            int g = (bm >> 5) + wr * 2;
            atomicAdd(&((float*)Cout)[g], p0);
            atomicAdd(&((float*)Cout)[g + 1], p1);
        }
        return;
    }
#pragma unroll
    for (int i = 0; i < 4; ++i) {
#pragma unroll
        for (int j = 0; j < 4; ++j) {
            int col = bn + ccol0 + j * 16;
            float bv = bias[col];
#pragma unroll
            for (int r = 0; r < 4; ++r) {
                int row = bm + crow0 + i * 16 + r;
                float v = acc[i][j][r] + bv;
                if (ACT == 1) v = fmaxf(v, 0.f);
                if (ACT == 2) v = tanhf(v);
                if (OUT_MODE == 1) {
                    ((__hip_bfloat16*)Cout)[(size_t)row * N + col] = __float2bfloat16(v);
                } else {
                    size_t prow = (size_t)(((row >> 7) << 5) | (row & 31));
                    size_t idx = prow * 2048 + (size_t)(((row >> 5) & 3) * 512 + col);
                    ((__hip_bfloat16*)Cout)[idx] = __float2bfloat16(v);
                }
            }
        }
    }
}

// ---------------- sigmoid over 512 graph logits --------------------------------
__global__ void sigmoid_k(const float* __restrict__ logits,
                          const float* __restrict__ blin, float* __restrict__ out) {
    int b = blockIdx.x * 256 + threadIdx.x;
    out[b] = 1.0f / (1.0f + expf(-(logits[b] + blin[0])));
}

extern "C" void kernel_launch(void* const* d_in, const int* in_sizes, int n_in,
                              void* d_out, int out_size, void* d_ws, size_t ws_size,
                              hipStream_t stream) {
    const float* x    = (const float*)d_in[0];
    const float* eattr= (const float*)d_in[1];
    const float* w1   = (const float*)d_in[2];
    const float* wg   = (const float*)d_in[3];
    const float* bg   = (const float*)d_in[4];
    const float* wc1  = (const float*)d_in[5];
    const float* bc1  = (const float*)d_in[6];
    const float* wc2  = (const float*)d_in[7];
    const float* bc2  = (const float*)d_in[8];
    const float* wlin = (const float*)d_in[9];
    const float* blin = (const float*)d_in[10];
    const int*   ei   = (const int*)d_in[11];
    const int* esrc = ei;
    const int* edst = ei + N_EDGES;
    float* out = (float*)d_out;

    // workspace layout (bytes, 16B aligned)
    char* ws = (char*)d_ws;
    float*          dinv   = (float*)(ws + 0);          // 262144
    int*            cnt    = (int*)(ws + 262144);       // 262144
    int*            rp     = (int*)(ws + 524288);       // 262160 (65537 ints)
    int*            cursor = (int*)(ws + 786688);       // 262144
    int*            ssrc   = (int*)(ws + 1048832);      // 2097152
    float*          scoef  = (float*)(ws + 3145984);    // 2097152
    __hip_bfloat16* WTbf   = (__hip_bfloat16*)(ws + 5243136);   // 131072
    __hip_bfloat16* ybf    = (__hip_bfloat16*)(ws + 5374208);   // 16777216
    __hip_bfloat16* V      = (__hip_bfloat16*)(ws + 22151424);  // 67108864
    __hip_bfloat16* act1   = (__hip_bfloat16*)(ws + 89260288);  // 16777216
    __hip_bfloat16* wc1bf  = (__hip_bfloat16*)(ws + 106037504); // 2097152
    __hip_bfloat16* wc2bf  = (__hip_bfloat16*)(ws + 108134656); // 262144
    __hip_bfloat16* xbf    = (__hip_bfloat16*)(ws + 108396800); // 16777216
    float*          logits = (float*)(ws + 125174016);  // 2048
    if (ws_size < (size_t)125176064) return;

    // 1) init (deg=1, cnt=0) + zero logits
    init_k<<<N_NODES / 256, 256, 0, stream>>>(dinv, cnt);  // dinv holds deg for now
    hipMemsetAsync(logits, 0, 2048, stream);

    // 2) degree + in-degree counts
    deg_cnt_k<<<N_EDGES / 256, 256, 0, stream>>>(edst, eattr, dinv, cnt);

    // 3) scan: rp/cursor + dinv = rsqrt(deg)  (in place: deg -> dinv)
    scan_k<<<1, 1024, 0, stream>>>(cnt, dinv, rp, cursor, dinv);

    // 4) scatter edges into CSR (needs dinv for coef)
    scatter_k<<<N_EDGES / 256, 256, 0, stream>>>(esrc, edst, eattr, dinv,
                                                 cursor, ssrc, scoef);

    // 5) merged prep: x/wc1/wc2 -> bf16, W_comb^T
    prep_k<<<9600, 256, 0, stream>>>(x, xbf, wc1, wc1bf, wc2, wc2bf, w1, wg, WTbf);

    // 6) gather SpMM on bf16 x -> ybf
    gather_k<<<N_NODES / 4, 256, 0, stream>>>(rp, ssrc, scoef,
                                              (const unsigned short*)xbf, dinv, ybf);

    // 7) h2 = tanh(y @ W_comb + b_gcn) -> V (bf16, rearranged layout)
    gemm_mfma_k<2, 2, 0><<<dim3(4, 512), 256, 0, stream>>>(
        ybf, WTbf, bg, V, nullptr, 65536, 512, 128);

    // 8) cnn1: act1 = relu(V @ wc1^T + bc1), XCD-swizzled 1D grid
    gemm_mfma_k<1, 1, 4><<<512, 256, 0, stream>>>(
        V, wc1bf, bc1, act1, nullptr, 16384, 512, 2048);

    // 9) cnn2 + final dot fused: logits[b] += sum relu(act1 @ wc2^T + bc2)*wlin
    gemm_mfma_k<1, 3, 0><<<dim3(2, 128), 256, 0, stream>>>(
        act1, wc2bf, bc2, logits, wlin, 16384, 256, 512);

    // 10) sigmoid
    sigmoid_k<<<2, 256, 0, stream>>>(logits, blin, out);
}

// Round 7
// 300.851 us; speedup vs baseline: 1.1142x; 1.1142x over previous
//
#include <hip/hip_runtime.h>
#include <hip/hip_bf16.h>

#define N_NODES 65536
#define N_EDGES 524288

typedef __attribute__((ext_vector_type(8))) short bf16x8;
typedef __attribute__((ext_vector_type(4))) float f32x4;

__device__ __forceinline__ float bf2f(unsigned short u) {
    union { unsigned int i; float f; } v;
    v.i = ((unsigned int)u) << 16;
    return v.f;
}

// ---------------- init: deg=1 (self-loop), cnt=0, logits=0 --------------------
__global__ void init_k(float* __restrict__ deg, int* __restrict__ cnt,
                       float* __restrict__ logits) {
    int i = blockIdx.x * 256 + threadIdx.x;
    deg[i] = 1.0f;
    cnt[i] = 0;
    if (i < 512) logits[i] = 0.0f;
}
__global__ void deg_cnt_k(const int* __restrict__ dst, const float* __restrict__ w,
                          float* __restrict__ deg, int* __restrict__ cnt) {
    int e = blockIdx.x * 256 + threadIdx.x;
    int d = dst[e];
    atomicAdd(&deg[d], w[e]);
    atomicAdd(&cnt[d], 1);
}

// ------- scan: exclusive prefix sum + dinv = rsqrt(deg) + cursor copy ---------
__global__ __launch_bounds__(1024) void scan_k(const int* __restrict__ cnt,
                                               const float* __restrict__ deg,
                                               int* __restrict__ rp,
                                               int* __restrict__ cursor,
                                               float* __restrict__ dinv) {
    __shared__ int sums[1024];
    int t = threadIdx.x;
    int base = t * 64;
    int s = 0;
#pragma unroll
    for (int i = 0; i < 64; ++i) s += cnt[base + i];
    sums[t] = s;
    __syncthreads();
    for (int d = 1; d < 1024; d <<= 1) {
        int v = (t >= d) ? sums[t - d] : 0;
        __syncthreads();
        if (t >= d) sums[t] += v;
        __syncthreads();
    }
    int run = (t == 0) ? 0 : sums[t - 1];
#pragma unroll
    for (int i = 0; i < 64; ++i) {
        rp[base + i] = run;
        cursor[base + i] = run;
        dinv[base + i] = rsqrtf(deg[base + i]);
        run += cnt[base + i];
    }
    if (t == 1023) rp[65536] = run;
}

// ------- scatter edges into dst-sorted CSR order, packed (src, coef) ----------
__global__ void scatter_k(const int* __restrict__ src, const int* __restrict__ dst,
                          const float* __restrict__ w, const float* __restrict__ dinv,
                          int* __restrict__ cursor, uint2* __restrict__ ep) {
    int e = blockIdx.x * 256 + threadIdx.x;
    int s = src[e], d = dst[e];
    int pos = atomicAdd(&cursor[d], 1);
    uint2 p;
    p.x = (unsigned int)s;
    p.y = __float_as_uint(dinv[s] * w[e] * dinv[d]);
    ep[pos] = p;  // single 8B store
}

// -------- merged weight/x prep: f2b(x) | f2b(wc1) | f2b(wc2) | wcomb ----------
// blocks [0,8192): x ; [8192,9216): wc1 ; [9216,9344): wc2 ; [9344,9600): wcomb
__global__ void prep_k(const float* __restrict__ x, __hip_bfloat16* __restrict__ xbf,
                       const float* __restrict__ wc1, __hip_bfloat16* __restrict__ wc1bf,
                       const float* __restrict__ wc2, __hip_bfloat16* __restrict__ wc2bf,
                       const float* __restrict__ w1, const float* __restrict__ wg,
                       __hip_bfloat16* __restrict__ WT) {
    int bid = blockIdx.x;
    if (bid < 9344) {
        const float* in;
        __hip_bfloat16* outp;
        int i;
        if (bid < 8192) { in = x; outp = xbf; i = bid * 1024 + threadIdx.x * 4; }
        else if (bid < 9216) { in = wc1; outp = wc1bf; i = (bid - 8192) * 1024 + threadIdx.x * 4; }
        else { in = wc2; outp = wc2bf; i = (bid - 9216) * 1024 + threadIdx.x * 4; }
        float4 v = *(const float4*)(in + i);
        alignas(8) __hip_bfloat16 tmp[4] = {__float2bfloat16(v.x), __float2bfloat16(v.y),
                                            __float2bfloat16(v.z), __float2bfloat16(v.w)};
        *(ushort4*)((unsigned short*)outp + i) = *(const ushort4*)tmp;
    } else {
        int t = (bid - 9344) * 256 + threadIdx.x;  // 512*128
        int f = t >> 7, c = t & 127;
        float s = 0.f;
#pragma unroll 8
        for (int m = 0; m < 128; ++m) s += w1[c * 128 + m] * wg[m * 512 + f];
        WT[t] = __float2bfloat16(s);  // WT[f*128 + c]
    }
}

// ---------------- gather SpMM, 4-deep ILP pipeline -----------------------------
// one wave per node; lane holds channels [2l, 2l+1] (one dword of bf16x2)
__global__ __launch_bounds__(256) void gather_k(const int* __restrict__ rp,
                                                const uint2* __restrict__ ep,
                                                const unsigned short* __restrict__ xbf,
                                                const float* __restrict__ dinv,
                                                __hip_bfloat16* __restrict__ ybf) {
    int n = (blockIdx.x * 256 + threadIdx.x) >> 6;
    int lane = threadIdx.x & 63;
    int beg = rp[n], end = rp[n + 1];
    float di = dinv[n];
    float accx, accy;
    {
        unsigned int u = *(const unsigned int*)(xbf + (size_t)n * 128 + lane * 2);
        float c = di * di;
        accx = c * bf2f((unsigned short)(u & 0xffff));
        accy = c * bf2f((unsigned short)(u >> 16));
    }
    int i = beg;
    // 4 independent x-row loads in flight per iteration (MLP, not serial chain)
    for (; i + 4 <= end; i += 4) {
        uint2 p0 = ep[i], p1 = ep[i + 1], p2 = ep[i + 2], p3 = ep[i + 3];
        unsigned int u0 = *(const unsigned int*)(xbf + (size_t)p0.x * 128 + lane * 2);
        unsigned int u1 = *(const unsigned int*)(xbf + (size_t)p1.x * 128 + lane * 2);
        unsigned int u2 = *(const unsigned int*)(xbf + (size_t)p2.x * 128 + lane * 2);
        unsigned int u3 = *(const unsigned int*)(xbf + (size_t)p3.x * 128 + lane * 2);
        float c0 = __uint_as_float(p0.y), c1 = __uint_as_float(p1.y);
        float c2 = __uint_as_float(p2.y), c3 = __uint_as_float(p3.y);
        accx += c0 * bf2f((unsigned short)(u0 & 0xffff));
        accy += c0 * bf2f((unsigned short)(u0 >> 16));
        accx += c1 * bf2f((unsigned short)(u1 & 0xffff));
        accy += c1 * bf2f((unsigned short)(u1 >> 16));
        accx += c2 * bf2f((unsigned short)(u2 & 0xffff));
        accy += c2 * bf2f((unsigned short)(u2 >> 16));
        accx += c3 * bf2f((unsigned short)(u3 & 0xffff));
        accy += c3 * bf2f((unsigned short)(u3 >> 16));
    }
    for (; i < end; ++i) {
        uint2 p = ep[i];
        unsigned int u = *(const unsigned int*)(xbf + (size_t)p.x * 128 + lane * 2);
        float c = __uint_as_float(p.y);
        accx += c * bf2f((unsigned short)(u & 0xffff));
        accy += c * bf2f((unsigned short)(u >> 16));
    }
    alignas(4) __hip_bfloat16 o[2] = {__float2bfloat16(accx), __float2bfloat16(accy)};
    *(unsigned int*)((unsigned short*)ybf + (size_t)n * 128 + lane * 2) =
        *(const unsigned int*)o;
}

// ---------------- async global -> LDS, 16B per lane ---------------------------
__device__ __forceinline__ void gll16(const void* g, void* l) {
    __builtin_amdgcn_global_load_lds(
        (const __attribute__((address_space(1))) void*)g,
        (__attribute__((address_space(3))) void*)l, 16, 0, 0);
}

// ---------------- bf16 MFMA GEMM, 2-phase double-buffered ---------------------
// C = act(A @ B^T + bias). A: MxK bf16 rm. B: NxK bf16 rm ((out,in) weights).
// ACT: 1 relu, 2 tanh.
// OUT_MODE: 1 bf16 rm, 2 bf16 rearrange-permute, 3 fused final dot -> atomicAdd
// SWIZ_NTX>0: 1D grid, XCD-chunked decode (N-blocks of one A-panel share an XCD)
template <int ACT, int OUT_MODE, int SWIZ_NTX>
__global__ __launch_bounds__(256) void gemm_mfma_k(
    const __hip_bfloat16* __restrict__ A, const __hip_bfloat16* __restrict__ B,
    const float* __restrict__ bias, void* __restrict__ Cout,
    const float* __restrict__ wlin, int M, int N, int K) {
    __shared__ char lds[32768];  // 2 bufs x (A 8KB | B 8KB)

    const int tid = threadIdx.x;
    const int lane = tid & 63, wid = tid >> 6;
    int bx, by;
    if (SWIZ_NTX > 0) {
        int orig = blockIdx.x;
        int per = gridDim.x / (8 * SWIZ_NTX);  // y-tiles per XCD
        int xcd = orig & 7, k = orig >> 3;
        by = xcd * per + k / SWIZ_NTX;
        bx = k % SWIZ_NTX;
    } else {
        bx = blockIdx.x;
        by = blockIdx.y;
    }
    const int bm = by * 128, bn = bx * 128;
    const int wr = wid >> 1, wc = wid & 1;

    const int srow = wid * 16 + (lane >> 2);
    const int skcol = (lane & 3) * 8;
    const __hip_bfloat16* Abase = A + (size_t)(bm + srow) * K + skcol;
    const __hip_bfloat16* Bbase = B + (size_t)(bn + srow) * K + skcol;
    const int ldso = wid * 1024;

    f32x4 acc[4][4] = {};

    const int lrow = lane & 15;
    const int lkb = (lane >> 4) * 16;
    const int nk = K >> 5;

    auto stage = [&](int buf, int kt) {
        char* la = lds + buf * 16384;
        char* lb = la + 8192;
        gll16(Abase + kt * 32,                  la + ldso);
        gll16(Abase + kt * 32 + (size_t)64 * K, la + 4096 + ldso);
        gll16(Bbase + kt * 32,                  lb + ldso);
        gll16(Bbase + kt * 32 + (size_t)64 * K, lb + 4096 + ldso);
    };

    stage(0, 0);
    __syncthreads();

    int cur = 0;
    for (int kt = 0; kt < nk; ++kt) {
        if (kt + 1 < nk) stage(cur ^ 1, kt + 1);
        const char* la = lds + cur * 16384;
        const char* lb = la + 8192;
        bf16x8 af[4], bfr[4];
#pragma unroll
        for (int i = 0; i < 4; ++i)
            af[i] = *(const bf16x8*)(la + (wr * 64 + i * 16 + lrow) * 64 + lkb);
#pragma unroll
        for (int j = 0; j < 4; ++j)
            bfr[j] = *(const bf16x8*)(lb + (wc * 64 + j * 16 + lrow) * 64 + lkb);
#pragma unroll
        for (int i = 0; i < 4; ++i)
#pragma unroll
            for (int j = 0; j < 4; ++j)
                acc[i][j] = __builtin_amdgcn_mfma_f32_16x16x32_bf16(
                    af[i], bfr[j], acc[i][j], 0, 0, 0);
        __syncthreads();
        cur ^= 1;
    }

    // epilogue: C/D layout col=lane&15, row=(lane>>4)*4+reg
    const int crow0 = wr * 64 + (lane >> 4) * 4;
    const int ccol0 = wc * 64 + (lane & 15);
    if (OUT_MODE == 3) {
        float p0 = 0.f, p1 = 0.f;
#pragma unroll
        for (int i = 0; i < 4; ++i)
#pragma unroll
            for (int j = 0; j < 4; ++j) {
                int col = bn + ccol0 + j * 16;  // p index
                float bv = bias[col];
#pragma unroll
                for (int r = 0; r < 4; ++r) {
                    int rloc = crow0 + i * 16 + r;
                    float v = fmaxf(acc[i][j][r] + bv, 0.f);
                    float wl = wlin[col * 32 + (rloc & 31)];
                    if (i < 2) p0 += v * wl; else p1 += v * wl;
                }
            }
#pragma unroll
        for (int off = 32; off > 0; off >>= 1) {
            p0 += __shfl_down(p0, off, 64);
            p1 += __shfl_down(p1, off, 64);
        }
        if (lane == 0) {
            int g = (bm >> 5) + wr * 2;
            atomicAdd(&((float*)Cout)[g], p0);
            atomicAdd(&((float*)Cout)[g + 1], p1);
        }
        return;
    }
#pragma unroll
    for (int i = 0; i < 4; ++i) {
#pragma unroll
        for (int j = 0; j < 4; ++j) {
            int col = bn + ccol0 + j * 16;
            float bv = bias[col];
#pragma unroll
            for (int r = 0; r < 4; ++r) {
                int row = bm + crow0 + i * 16 + r;
                float v = acc[i][j][r] + bv;
                if (ACT == 1) v = fmaxf(v, 0.f);
                if (ACT == 2) v = tanhf(v);
                if (OUT_MODE == 1) {
                    ((__hip_bfloat16*)Cout)[(size_t)row * N + col] = __float2bfloat16(v);
                } else {
                    size_t prow = (size_t)(((row >> 7) << 5) | (row & 31));
                    size_t idx = prow * 2048 + (size_t)(((row >> 5) & 3) * 512 + col);
                    ((__hip_bfloat16*)Cout)[idx] = __float2bfloat16(v);
                }
            }
        }
    }
}

// ---------------- sigmoid over 512 graph logits --------------------------------
__global__ void sigmoid_k(const float* __restrict__ logits,
                          const float* __restrict__ blin, float* __restrict__ out) {
    int b = blockIdx.x * 256 + threadIdx.x;
    out[b] = 1.0f / (1.0f + expf(-(logits[b] + blin[0])));
}

extern "C" void kernel_launch(void* const* d_in, const int* in_sizes, int n_in,
                              void* d_out, int out_size, void* d_ws, size_t ws_size,
                              hipStream_t stream) {
    const float* x    = (const float*)d_in[0];
    const float* eattr= (const float*)d_in[1];
    const float* w1   = (const float*)d_in[2];
    const float* wg   = (const float*)d_in[3];
    const float* bg   = (const float*)d_in[4];
    const float* wc1  = (const float*)d_in[5];
    const float* bc1  = (const float*)d_in[6];
    const float* wc2  = (const float*)d_in[7];
    const float* bc2  = (const float*)d_in[8];
    const float* wlin = (const float*)d_in[9];
    const float* blin = (const float*)d_in[10];
    const int*   ei   = (const int*)d_in[11];
    const int* esrc = ei;
    const int* edst = ei + N_EDGES;
    float* out = (float*)d_out;

    // workspace layout (bytes, 16B aligned)
    char* ws = (char*)d_ws;
    float*          dinv   = (float*)(ws + 0);          // 262144
    int*            cnt    = (int*)(ws + 262144);       // 262144
    int*            rp     = (int*)(ws + 524288);       // 262160 (65537 ints)
    int*            cursor = (int*)(ws + 786688);       // 262144
    uint2*          ep     = (uint2*)(ws + 1048832);    // 4194304 (packed src,coef)
    __hip_bfloat16* WTbf   = (__hip_bfloat16*)(ws + 5243136);   // 131072
    __hip_bfloat16* ybf    = (__hip_bfloat16*)(ws + 5374208);   // 16777216
    __hip_bfloat16* V      = (__hip_bfloat16*)(ws + 22151424);  // 67108864
    __hip_bfloat16* act1   = (__hip_bfloat16*)(ws + 89260288);  // 16777216
    __hip_bfloat16* wc1bf  = (__hip_bfloat16*)(ws + 106037504); // 2097152
    __hip_bfloat16* wc2bf  = (__hip_bfloat16*)(ws + 108134656); // 262144
    __hip_bfloat16* xbf    = (__hip_bfloat16*)(ws + 108396800); // 16777216
    float*          logits = (float*)(ws + 125174016);  // 2048
    if (ws_size < (size_t)125176064) return;

    // 1) init (deg=1, cnt=0, logits=0)
    init_k<<<N_NODES / 256, 256, 0, stream>>>(dinv, cnt, logits);

    // 2) degree + in-degree counts
    deg_cnt_k<<<N_EDGES / 256, 256, 0, stream>>>(edst, eattr, dinv, cnt);

    // 3) scan: rp/cursor + dinv = rsqrt(deg)  (in place: deg -> dinv)
    scan_k<<<1, 1024, 0, stream>>>(cnt, dinv, rp, cursor, dinv);

    // 4) scatter edges into CSR, packed 8B records
    scatter_k<<<N_EDGES / 256, 256, 0, stream>>>(esrc, edst, eattr, dinv,
                                                 cursor, ep);

    // 5) merged prep: x/wc1/wc2 -> bf16, W_comb^T
    prep_k<<<9600, 256, 0, stream>>>(x, xbf, wc1, wc1bf, wc2, wc2bf, w1, wg, WTbf);

    // 6) gather SpMM on bf16 x -> ybf (4-deep ILP)
    gather_k<<<N_NODES / 4, 256, 0, stream>>>(rp, ep,
                                              (const unsigned short*)xbf, dinv, ybf);

    // 7) h2 = tanh(y @ W_comb + b_gcn) -> V (bf16, rearranged layout)
    gemm_mfma_k<2, 2, 0><<<dim3(4, 512), 256, 0, stream>>>(
        ybf, WTbf, bg, V, nullptr, 65536, 512, 128);

    // 8) cnn1: act1 = relu(V @ wc1^T + bc1), XCD-swizzled 1D grid
    gemm_mfma_k<1, 1, 4><<<512, 256, 0, stream>>>(
        V, wc1bf, bc1, act1, nullptr, 16384, 512, 2048);

    // 9) cnn2 + final dot fused: logits[b] += sum relu(act1 @ wc2^T + bc2)*wlin
    gemm_mfma_k<1, 3, 0><<<dim3(2, 128), 256, 0, stream>>>(
        act1, wc2bf, bc2, logits, wlin, 16384, 256, 512);

    // 10) sigmoid
    sigmoid_k<<<2, 256, 0, stream>>>(logits, blin, out);
}

// Round 8
// 251.786 us; speedup vs baseline: 1.3313x; 1.1949x over previous
//
#include <hip/hip_runtime.h>
#include <hip/hip_bf16.h>

#define N_NODES 65536
#define N_EDGES 524288

typedef __attribute__((ext_vector_type(8))) short bf16x8;
typedef __attribute__((ext_vector_type(4))) float f32x4;

__device__ __forceinline__ float bf2f(unsigned short u) {
    union { unsigned int i; float f; } v;
    v.i = ((unsigned int)u) << 16;
    return v.f;
}

// ---------------- init: deg=1 (self-loop), cnt=0, logits=0 --------------------
__global__ void init_k(float* __restrict__ deg, int* __restrict__ cnt,
                       float* __restrict__ logits) {
    int i = blockIdx.x * 256 + threadIdx.x;
    deg[i] = 1.0f;
    cnt[i] = 0;
    if (i < 512) logits[i] = 0.0f;
}
__global__ void deg_cnt_k(const int* __restrict__ dst, const float* __restrict__ w,
                          float* __restrict__ deg, int* __restrict__ cnt) {
    int e = blockIdx.x * 256 + threadIdx.x;
    int d = dst[e];
    atomicAdd(&deg[d], w[e]);
    atomicAdd(&cnt[d], 1);
}

// ------- hierarchical exclusive scan of cnt[65536] -> rp, cursor, dinv --------
// scan1: per-block (256 elems) exclusive scan -> rp partial, block sums -> bsum
__global__ __launch_bounds__(256) void scan1_k(const int* __restrict__ cnt,
                                               int* __restrict__ rp,
                                               int* __restrict__ bsum) {
    __shared__ int s[256];
    int t = threadIdx.x, g = blockIdx.x * 256 + t;
    int v = cnt[g];
    s[t] = v;
    __syncthreads();
    for (int d = 1; d < 256; d <<= 1) {
        int u = (t >= d) ? s[t - d] : 0;
        __syncthreads();
        s[t] += u;
        __syncthreads();
    }
    rp[g] = s[t] - v;  // exclusive within block
    if (t == 255) bsum[blockIdx.x] = s[255];
}
// scan2: exclusive scan of the 256 block sums (in place) + total -> rp[65536]
__global__ __launch_bounds__(256) void scan2_k(int* __restrict__ bsum,
                                               int* __restrict__ rp) {
    __shared__ int s[256];
    int t = threadIdx.x;
    int v = bsum[t];
    s[t] = v;
    __syncthreads();
    for (int d = 1; d < 256; d <<= 1) {
        int u = (t >= d) ? s[t - d] : 0;
        __syncthreads();
        s[t] += u;
        __syncthreads();
    }
    bsum[t] = s[t] - v;  // exclusive block offsets
    if (t == 255) rp[65536] = s[255];
}
// scan3: apply block offsets; emit final rp, cursor, dinv = rsqrt(deg)
__global__ __launch_bounds__(256) void scan3_k(int* __restrict__ rp,
                                               const int* __restrict__ bsum,
                                               int* __restrict__ cursor,
                                               const float* __restrict__ deg,
                                               float* __restrict__ dinv) {
    int t = threadIdx.x, g = blockIdx.x * 256 + t;
    int r = rp[g] + bsum[blockIdx.x];
    rp[g] = r;
    cursor[g] = r;
    dinv[g] = rsqrtf(deg[g]);
}

// ------- scatter edges into dst-sorted CSR order, packed (src, coef) ----------
__global__ void scatter_k(const int* __restrict__ src, const int* __restrict__ dst,
                          const float* __restrict__ w, const float* __restrict__ dinv,
                          int* __restrict__ cursor, uint2* __restrict__ ep) {
    int e = blockIdx.x * 256 + threadIdx.x;
    int s = src[e], d = dst[e];
    int pos = atomicAdd(&cursor[d], 1);
    uint2 p;
    p.x = (unsigned int)s;
    p.y = __float_as_uint(dinv[s] * w[e] * dinv[d]);
    ep[pos] = p;  // single 8B store
}

// -------- merged weight/x prep: f2b(x) | f2b(wc1) | f2b(wc2) | wcomb ----------
// blocks [0,8192): x ; [8192,9216): wc1 ; [9216,9344): wc2 ; [9344,9600): wcomb
__global__ void prep_k(const float* __restrict__ x, __hip_bfloat16* __restrict__ xbf,
                       const float* __restrict__ wc1, __hip_bfloat16* __restrict__ wc1bf,
                       const float* __restrict__ wc2, __hip_bfloat16* __restrict__ wc2bf,
                       const float* __restrict__ w1, const float* __restrict__ wg,
                       __hip_bfloat16* __restrict__ WT) {
    int bid = blockIdx.x;
    if (bid < 9344) {
        const float* in;
        __hip_bfloat16* outp;
        int i;
        if (bid < 8192) { in = x; outp = xbf; i = bid * 1024 + threadIdx.x * 4; }
        else if (bid < 9216) { in = wc1; outp = wc1bf; i = (bid - 8192) * 1024 + threadIdx.x * 4; }
        else { in = wc2; outp = wc2bf; i = (bid - 9216) * 1024 + threadIdx.x * 4; }
        float4 v = *(const float4*)(in + i);
        alignas(8) __hip_bfloat16 tmp[4] = {__float2bfloat16(v.x), __float2bfloat16(v.y),
                                            __float2bfloat16(v.z), __float2bfloat16(v.w)};
        *(ushort4*)((unsigned short*)outp + i) = *(const ushort4*)tmp;
    } else {
        int t = (bid - 9344) * 256 + threadIdx.x;  // 512*128
        int f = t >> 7, c = t & 127;
        float s = 0.f;
#pragma unroll 8
        for (int m = 0; m < 128; ++m) s += w1[c * 128 + m] * wg[m * 512 + f];
        WT[t] = __float2bfloat16(s);  // WT[f*128 + c]
    }
}

// ---------------- gather SpMM, 4-deep ILP pipeline -----------------------------
// one wave per node; lane holds channels [2l, 2l+1] (one dword of bf16x2)
__global__ __launch_bounds__(256) void gather_k(const int* __restrict__ rp,
                                                const uint2* __restrict__ ep,
                                                const unsigned short* __restrict__ xbf,
                                                const float* __restrict__ dinv,
                                                __hip_bfloat16* __restrict__ ybf) {
    int n = (blockIdx.x * 256 + threadIdx.x) >> 6;
    int lane = threadIdx.x & 63;
    int beg = rp[n], end = rp[n + 1];
    float di = dinv[n];
    float accx, accy;
    {
        unsigned int u = *(const unsigned int*)(xbf + (size_t)n * 128 + lane * 2);
        float c = di * di;
        accx = c * bf2f((unsigned short)(u & 0xffff));
        accy = c * bf2f((unsigned short)(u >> 16));
    }
    int i = beg;
    for (; i + 4 <= end; i += 4) {
        uint2 p0 = ep[i], p1 = ep[i + 1], p2 = ep[i + 2], p3 = ep[i + 3];
        unsigned int u0 = *(const unsigned int*)(xbf + (size_t)p0.x * 128 + lane * 2);
        unsigned int u1 = *(const unsigned int*)(xbf + (size_t)p1.x * 128 + lane * 2);
        unsigned int u2 = *(const unsigned int*)(xbf + (size_t)p2.x * 128 + lane * 2);
        unsigned int u3 = *(const unsigned int*)(xbf + (size_t)p3.x * 128 + lane * 2);
        float c0 = __uint_as_float(p0.y), c1 = __uint_as_float(p1.y);
        float c2 = __uint_as_float(p2.y), c3 = __uint_as_float(p3.y);
        accx += c0 * bf2f((unsigned short)(u0 & 0xffff));
        accy += c0 * bf2f((unsigned short)(u0 >> 16));
        accx += c1 * bf2f((unsigned short)(u1 & 0xffff));
        accy += c1 * bf2f((unsigned short)(u1 >> 16));
        accx += c2 * bf2f((unsigned short)(u2 & 0xffff));
        accy += c2 * bf2f((unsigned short)(u2 >> 16));
        accx += c3 * bf2f((unsigned short)(u3 & 0xffff));
        accy += c3 * bf2f((unsigned short)(u3 >> 16));
    }
    for (; i < end; ++i) {
        uint2 p = ep[i];
        unsigned int u = *(const unsigned int*)(xbf + (size_t)p.x * 128 + lane * 2);
        float c = __uint_as_float(p.y);
        accx += c * bf2f((unsigned short)(u & 0xffff));
        accy += c * bf2f((unsigned short)(u >> 16));
    }
    alignas(4) __hip_bfloat16 o[2] = {__float2bfloat16(accx), __float2bfloat16(accy)};
    *(unsigned int*)((unsigned short*)ybf + (size_t)n * 128 + lane * 2) =
        *(const unsigned int*)o;
}

// ---------------- async global -> LDS, 16B per lane ---------------------------
__device__ __forceinline__ void gll16(const void* g, void* l) {
    __builtin_amdgcn_global_load_lds(
        (const __attribute__((address_space(1))) void*)g,
        (__attribute__((address_space(3))) void*)l, 16, 0, 0);
}

// ---------------- bf16 MFMA GEMM, 2-phase double-buffered ---------------------
// C = act(A @ B^T + bias). A: MxK bf16 rm. B: NxK bf16 rm ((out,in) weights).
// ACT: 1 relu, 2 tanh.
// OUT_MODE: 1 bf16 rm, 2 bf16 rearrange-permute, 3 fused final dot -> atomicAdd
// SWIZ_NTX>0: 1D grid, XCD-chunked decode (N-blocks of one A-panel share an XCD)
template <int ACT, int OUT_MODE, int SWIZ_NTX>
__global__ __launch_bounds__(256) void gemm_mfma_k(
    const __hip_bfloat16* __restrict__ A, const __hip_bfloat16* __restrict__ B,
    const float* __restrict__ bias, void* __restrict__ Cout,
    const float* __restrict__ wlin, int M, int N, int K) {
    __shared__ char lds[32768];  // 2 bufs x (A 8KB | B 8KB)

    const int tid = threadIdx.x;
    const int lane = tid & 63, wid = tid >> 6;
    int bx, by;
    if (SWIZ_NTX > 0) {
        int orig = blockIdx.x;
        int per = gridDim.x / (8 * SWIZ_NTX);  // y-tiles per XCD
        int xcd = orig & 7, k = orig >> 3;
        by = xcd * per + k / SWIZ_NTX;
        bx = k % SWIZ_NTX;
    } else {
        bx = blockIdx.x;
        by = blockIdx.y;
    }
    const int bm = by * 128, bn = bx * 128;
    const int wr = wid >> 1, wc = wid & 1;

    const int srow = wid * 16 + (lane >> 2);
    const int skcol = (lane & 3) * 8;
    const __hip_bfloat16* Abase = A + (size_t)(bm + srow) * K + skcol;
    const __hip_bfloat16* Bbase = B + (size_t)(bn + srow) * K + skcol;
    const int ldso = wid * 1024;

    f32x4 acc[4][4] = {};

    const int lrow = lane & 15;
    const int lkb = (lane >> 4) * 16;
    const int nk = K >> 5;

    auto stage = [&](int buf, int kt) {
        char* la = lds + buf * 16384;
        char* lb = la + 8192;
        gll16(Abase + kt * 32,                  la + ldso);
        gll16(Abase + kt * 32 + (size_t)64 * K, la + 4096 + ldso);
        gll16(Bbase + kt * 32,                  lb + ldso);
        gll16(Bbase + kt * 32 + (size_t)64 * K, lb + 4096 + ldso);
    };

    stage(0, 0);
    __syncthreads();

    int cur = 0;
    for (int kt = 0; kt < nk; ++kt) {
        if (kt + 1 < nk) stage(cur ^ 1, kt + 1);
        const char* la = lds + cur * 16384;
        const char* lb = la + 8192;
        bf16x8 af[4], bfr[4];
#pragma unroll
        for (int i = 0; i < 4; ++i)
            af[i] = *(const bf16x8*)(la + (wr * 64 + i * 16 + lrow) * 64 + lkb);
#pragma unroll
        for (int j = 0; j < 4; ++j)
            bfr[j] = *(const bf16x8*)(lb + (wc * 64 + j * 16 + lrow) * 64 + lkb);
#pragma unroll
        for (int i = 0; i < 4; ++i)
#pragma unroll
            for (int j = 0; j < 4; ++j)
                acc[i][j] = __builtin_amdgcn_mfma_f32_16x16x32_bf16(
                    af[i], bfr[j], acc[i][j], 0, 0, 0);
        __syncthreads();
        cur ^= 1;
    }

    // epilogue: C/D layout col=lane&15, row=(lane>>4)*4+reg
    const int crow0 = wr * 64 + (lane >> 4) * 4;
    const int ccol0 = wc * 64 + (lane & 15);
    if (OUT_MODE == 3) {
        float p0 = 0.f, p1 = 0.f;
#pragma unroll
        for (int i = 0; i < 4; ++i)
#pragma unroll
            for (int j = 0; j < 4; ++j) {
                int col = bn + ccol0 + j * 16;  // p index
                float bv = bias[col];
#pragma unroll
                for (int r = 0; r < 4; ++r) {
                    int rloc = crow0 + i * 16 + r;
                    float v = fmaxf(acc[i][j][r] + bv, 0.f);
                    float wl = wlin[col * 32 + (rloc & 31)];
                    if (i < 2) p0 += v * wl; else p1 += v * wl;
                }
            }
#pragma unroll
        for (int off = 32; off > 0; off >>= 1) {
            p0 += __shfl_down(p0, off, 64);
            p1 += __shfl_down(p1, off, 64);
        }
        if (lane == 0) {
            int g = (bm >> 5) + wr * 2;
            atomicAdd(&((float*)Cout)[g], p0);
            atomicAdd(&((float*)Cout)[g + 1], p1);
        }
        return;
    }
#pragma unroll
    for (int i = 0; i < 4; ++i) {
#pragma unroll
        for (int j = 0; j < 4; ++j) {
            int col = bn + ccol0 + j * 16;
            float bv = bias[col];
#pragma unroll
            for (int r = 0; r < 4; ++r) {
                int row = bm + crow0 + i * 16 + r;
                float v = acc[i][j][r] + bv;
                if (ACT == 1) v = fmaxf(v, 0.f);
                if (ACT == 2) v = tanhf(v);
                if (OUT_MODE == 1) {
                    ((__hip_bfloat16*)Cout)[(size_t)row * N + col] = __float2bfloat16(v);
                } else {
                    size_t prow = (size_t)(((row >> 7) << 5) | (row & 31));
                    size_t idx = prow * 2048 + (size_t)(((row >> 5) & 3) * 512 + col);
                    ((__hip_bfloat16*)Cout)[idx] = __float2bfloat16(v);
                }
            }
        }
    }
}

// ---------------- sigmoid over 512 graph logits --------------------------------
__global__ void sigmoid_k(const float* __restrict__ logits,
                          const float* __restrict__ blin, float* __restrict__ out) {
    int b = blockIdx.x * 256 + threadIdx.x;
    out[b] = 1.0f / (1.0f + expf(-(logits[b] + blin[0])));
}

extern "C" void kernel_launch(void* const* d_in, const int* in_sizes, int n_in,
                              void* d_out, int out_size, void* d_ws, size_t ws_size,
                              hipStream_t stream) {
    const float* x    = (const float*)d_in[0];
    const float* eattr= (const float*)d_in[1];
    const float* w1   = (const float*)d_in[2];
    const float* wg   = (const float*)d_in[3];
    const float* bg   = (const float*)d_in[4];
    const float* wc1  = (const float*)d_in[5];
    const float* bc1  = (const float*)d_in[6];
    const float* wc2  = (const float*)d_in[7];
    const float* bc2  = (const float*)d_in[8];
    const float* wlin = (const float*)d_in[9];
    const float* blin = (const float*)d_in[10];
    const int*   ei   = (const int*)d_in[11];
    const int* esrc = ei;
    const int* edst = ei + N_EDGES;
    float* out = (float*)d_out;

    // workspace layout (bytes, 16B aligned)
    char* ws = (char*)d_ws;
    float*          dinv   = (float*)(ws + 0);          // 262144
    int*            cnt    = (int*)(ws + 262144);       // 262144
    int*            rp     = (int*)(ws + 524288);       // 262160 (65537 ints)
    int*            cursor = (int*)(ws + 786688);       // 262144
    uint2*          ep     = (uint2*)(ws + 1048832);    // 4194304 (packed src,coef)
    __hip_bfloat16* WTbf   = (__hip_bfloat16*)(ws + 5243136);   // 131072
    __hip_bfloat16* ybf    = (__hip_bfloat16*)(ws + 5374208);   // 16777216
    __hip_bfloat16* V      = (__hip_bfloat16*)(ws + 22151424);  // 67108864
    __hip_bfloat16* act1   = (__hip_bfloat16*)(ws + 89260288);  // 16777216
    __hip_bfloat16* wc1bf  = (__hip_bfloat16*)(ws + 106037504); // 2097152
    __hip_bfloat16* wc2bf  = (__hip_bfloat16*)(ws + 108134656); // 262144
    __hip_bfloat16* xbf    = (__hip_bfloat16*)(ws + 108396800); // 16777216
    float*          logits = (float*)(ws + 125174016);  // 2048
    int*            bsum   = (int*)(ws + 125176064);    // 1024
    if (ws_size < (size_t)125177088) return;

    // 1) init (deg=1, cnt=0, logits=0)
    init_k<<<N_NODES / 256, 256, 0, stream>>>(dinv, cnt, logits);

    // 2) degree + in-degree counts
    deg_cnt_k<<<N_EDGES / 256, 256, 0, stream>>>(edst, eattr, dinv, cnt);

    // 3) hierarchical scan: rp/cursor + dinv = rsqrt(deg)  (deg -> dinv in place)
    scan1_k<<<256, 256, 0, stream>>>(cnt, rp, bsum);
    scan2_k<<<1, 256, 0, stream>>>(bsum, rp);
    scan3_k<<<256, 256, 0, stream>>>(rp, bsum, cursor, dinv, dinv);

    // 4) scatter edges into CSR, packed 8B records
    scatter_k<<<N_EDGES / 256, 256, 0, stream>>>(esrc, edst, eattr, dinv,
                                                 cursor, ep);

    // 5) merged prep: x/wc1/wc2 -> bf16, W_comb^T
    prep_k<<<9600, 256, 0, stream>>>(x, xbf, wc1, wc1bf, wc2, wc2bf, w1, wg, WTbf);

    // 6) gather SpMM on bf16 x -> ybf (4-deep ILP)
    gather_k<<<N_NODES / 4, 256, 0, stream>>>(rp, ep,
                                              (const unsigned short*)xbf, dinv, ybf);

    // 7) h2 = tanh(y @ W_comb + b_gcn) -> V (bf16, rearranged layout)
    gemm_mfma_k<2, 2, 0><<<dim3(4, 512), 256, 0, stream>>>(
        ybf, WTbf, bg, V, nullptr, 65536, 512, 128);

    // 8) cnn1: act1 = relu(V @ wc1^T + bc1), XCD-swizzled 1D grid
    gemm_mfma_k<1, 1, 4><<<512, 256, 0, stream>>>(
        V, wc1bf, bc1, act1, nullptr, 16384, 512, 2048);

    // 9) cnn2 + final dot fused: logits[b] += sum relu(act1 @ wc2^T + bc2)*wlin
    gemm_mfma_k<1, 3, 0><<<dim3(2, 128), 256, 0, stream>>>(
        act1, wc2bf, bc2, logits, wlin, 16384, 256, 512);

    // 10) sigmoid
    sigmoid_k<<<2, 256, 0, stream>>>(logits, blin, out);
}